// Round 1
// baseline (3311.952 us; speedup 1.0000x reference)
//
#include <hip/hip_runtime.h>
#include <hip/hip_bf16.h>

#define TN 49      // tokens per window (7*7)
#define TC 192     // channels
#define NH 6       // heads
#define HD 32      // head dim

static constexpr float SCALE = 0.17677669529663687f;  // 32^-0.5

// ---------------------------------------------------------------------------
// Kernel 1: per-window fused qkv + attention core. One block per window.
// Writes attention output (B_, N, C) fp32 into workspace.
// ---------------------------------------------------------------------------
__global__ __launch_bounds__(256) void attn_core_kernel(
    const float* __restrict__ x, const float* __restrict__ mask,
    const float* __restrict__ bt, const float* __restrict__ qw,
    const float* __restrict__ qb, const int* __restrict__ ridx,
    float* __restrict__ ao, int nW)
{
    __shared__ __align__(16) float xs[TN * TC];   // 37632 B
    __shared__ __align__(16) float qs[TN * HD];   // 6272 B (q, later reused for v)
    __shared__ __align__(16) float ks[TN * HD];   // 6272 B
    __shared__ __align__(16) float at[TN * TN];   // 9604 B   -> total 59780 B

    const int b  = blockIdx.x;
    const int t  = threadIdx.x;
    const int td = t & 31;      // 32 lanes over head-dim / out-channel
    const int tn = t >> 5;      // 8 groups over rows

    // ---- stage x[b] into LDS (vectorized, coalesced) ----
    {
        const float4* xg = (const float4*)(x + (size_t)b * TN * TC);
        float4* xl = (float4*)xs;
        for (int i = t; i < TN * TC / 4; i += 256) xl[i] = xg[i];
    }
    __syncthreads();

    // per-thread row offsets (7 rows, clamped for the 7 invalid tail rows)
    int roff[7];
#pragma unroll
    for (int j = 0; j < 7; ++j) {
        int n = tn + 8 * j;
        roff[j] = (n < TN ? n : 0) * (TC / 4);
    }
    const float4* xl4 = (const float4*)xs;
    const int w = b % nW;
    const float* mrow = mask + (size_t)w * TN * TN;

    for (int h = 0; h < NH; ++h) {
        // ---- q,k for this head: (49 x 192) @ (192 x 32) twice ----
        {
            const float4* wq = (const float4*)(qw + (size_t)(h * HD + td) * TC);
            const float4* wk = (const float4*)(qw + (size_t)(TC + h * HD + td) * TC);
            const float bq = qb[h * HD + td];
            const float bk = qb[TC + h * HD + td];
            float aq[7], ak[7];
#pragma unroll
            for (int j = 0; j < 7; ++j) { aq[j] = 0.f; ak[j] = 0.f; }
            for (int c4 = 0; c4 < TC / 4; ++c4) {
                float4 wqv = wq[c4];
                float4 wkv = wk[c4];
#pragma unroll
                for (int j = 0; j < 7; ++j) {
                    float4 xv = xl4[roff[j] + c4];
                    aq[j] = fmaf(xv.x, wqv.x, aq[j]);
                    aq[j] = fmaf(xv.y, wqv.y, aq[j]);
                    aq[j] = fmaf(xv.z, wqv.z, aq[j]);
                    aq[j] = fmaf(xv.w, wqv.w, aq[j]);
                    ak[j] = fmaf(xv.x, wkv.x, ak[j]);
                    ak[j] = fmaf(xv.y, wkv.y, ak[j]);
                    ak[j] = fmaf(xv.z, wkv.z, ak[j]);
                    ak[j] = fmaf(xv.w, wkv.w, ak[j]);
                }
            }
#pragma unroll
            for (int j = 0; j < 7; ++j) {
                int n = tn + 8 * j;
                if (n < TN) {
                    qs[n * HD + td] = (aq[j] + bq) * SCALE;
                    ks[n * HD + td] = ak[j] + bk;
                }
            }
        }
        __syncthreads();

        // ---- logits: attn[n][m] = q[n].k[m] + bias + mask ----
        for (int i = t; i < TN * TN; i += 256) {
            int n = i / TN, m = i - n * TN;
            const float* qr = qs + n * HD;
            const float* kr = ks + m * HD;
            float s = 0.f;
#pragma unroll
            for (int d = 0; d < HD; ++d) s = fmaf(qr[d], kr[d], s);
            s += bt[ridx[i] * NH + h] + mrow[i];
            at[i] = s;
        }
        __syncthreads();

        // ---- softmax per row (thread t handles row t) ----
        if (t < TN) {
            float* r = at + t * TN;
            float mx = -1e30f;
            for (int m = 0; m < TN; ++m) mx = fmaxf(mx, r[m]);
            float sum = 0.f;
            for (int m = 0; m < TN; ++m) { float e = __expf(r[m] - mx); r[m] = e; sum += e; }
            float inv = 1.f / sum;
            for (int m = 0; m < TN; ++m) r[m] *= inv;
        }
        __syncthreads();

        // ---- v for this head (into qs buffer; q no longer needed) ----
        {
            const float4* wv = (const float4*)(qw + (size_t)(2 * TC + h * HD + td) * TC);
            const float bv = qb[2 * TC + h * HD + td];
            float av[7];
#pragma unroll
            for (int j = 0; j < 7; ++j) av[j] = 0.f;
            for (int c4 = 0; c4 < TC / 4; ++c4) {
                float4 wvv = wv[c4];
#pragma unroll
                for (int j = 0; j < 7; ++j) {
                    float4 xv = xl4[roff[j] + c4];
                    av[j] = fmaf(xv.x, wvv.x, av[j]);
                    av[j] = fmaf(xv.y, wvv.y, av[j]);
                    av[j] = fmaf(xv.z, wvv.z, av[j]);
                    av[j] = fmaf(xv.w, wvv.w, av[j]);
                }
            }
            __syncthreads();   // ensure logits-phase reads of qs are done on all waves
#pragma unroll
            for (int j = 0; j < 7; ++j) {
                int n = tn + 8 * j;
                if (n < TN) qs[n * HD + td] = av[j] + bv;
            }
        }
        __syncthreads();

        // ---- out_h = attn @ v, write to workspace ----
        {
            int aoff[7];
#pragma unroll
            for (int j = 0; j < 7; ++j) {
                int n = tn + 8 * j;
                aoff[j] = (n < TN ? n : 0) * TN;
            }
            float acc[7];
#pragma unroll
            for (int j = 0; j < 7; ++j) acc[j] = 0.f;
            for (int m = 0; m < TN; ++m) {
                float vv = qs[m * HD + td];
#pragma unroll
                for (int j = 0; j < 7; ++j)
                    acc[j] = fmaf(at[aoff[j] + m], vv, acc[j]);
            }
            float* aop = ao + (size_t)b * TN * TC + h * HD + td;
#pragma unroll
            for (int j = 0; j < 7; ++j) {
                int n = tn + 8 * j;
                if (n < TN) aop[n * TC] = acc[j];
            }
        }
        __syncthreads();
    }
}

// ---------------------------------------------------------------------------
// Kernel 2: output projection, (B_*N, 192) @ (192, 192)^T + bias
// ---------------------------------------------------------------------------
__global__ __launch_bounds__(256) void proj_kernel(
    const float* __restrict__ ao, const float* __restrict__ pw,
    const float* __restrict__ pb, float* __restrict__ out)
{
    __shared__ __align__(16) float as_[TN * TC];
    const int b  = blockIdx.x;
    const int t  = threadIdx.x;
    const int td = t & 31;
    const int tn = t >> 5;

    {
        const float4* ag = (const float4*)(ao + (size_t)b * TN * TC);
        float4* al = (float4*)as_;
        for (int i = t; i < TN * TC / 4; i += 256) al[i] = ag[i];
    }
    __syncthreads();

    int roff[7];
#pragma unroll
    for (int j = 0; j < 7; ++j) {
        int n = tn + 8 * j;
        roff[j] = (n < TN ? n : 0) * (TC / 4);
    }
    const float4* al4 = (const float4*)as_;

    for (int cc = 0; cc < TC / 32; ++cc) {
        const int c = cc * 32 + td;
        const float4* wr = (const float4*)(pw + (size_t)c * TC);
        const float bias = pb[c];
        float acc[7];
#pragma unroll
        for (int j = 0; j < 7; ++j) acc[j] = 0.f;
        for (int k4 = 0; k4 < TC / 4; ++k4) {
            float4 wv = wr[k4];
#pragma unroll
            for (int j = 0; j < 7; ++j) {
                float4 xv = al4[roff[j] + k4];
                acc[j] = fmaf(xv.x, wv.x, acc[j]);
                acc[j] = fmaf(xv.y, wv.y, acc[j]);
                acc[j] = fmaf(xv.z, wv.z, acc[j]);
                acc[j] = fmaf(xv.w, wv.w, acc[j]);
            }
        }
        float* op = out + (size_t)b * TN * TC + c;
#pragma unroll
        for (int j = 0; j < 7; ++j) {
            int n = tn + 8 * j;
            if (n < TN) op[n * TC] = acc[j] + bias;
        }
    }
}

extern "C" void kernel_launch(void* const* d_in, const int* in_sizes, int n_in,
                              void* d_out, int out_size, void* d_ws, size_t ws_size,
                              hipStream_t stream) {
    const float* x    = (const float*)d_in[0];
    const float* mask = (const float*)d_in[1];
    const float* bt   = (const float*)d_in[2];
    const float* qw   = (const float*)d_in[3];
    const float* qb   = (const float*)d_in[4];
    const float* pw   = (const float*)d_in[5];
    const float* pb   = (const float*)d_in[6];
    const int*   ridx = (const int*)d_in[7];

    const int B  = in_sizes[0] / (TN * TC);   // 4096
    const int nW = in_sizes[1] / (TN * TN);   // 64

    float* ao  = (float*)d_ws;                // (B, N, C) fp32 = 150.5 MB
    float* out = (float*)d_out;

    hipLaunchKernelGGL(attn_core_kernel, dim3(B), dim3(256), 0, stream,
                       x, mask, bt, qw, qb, ridx, ao, nW);
    hipLaunchKernelGGL(proj_kernel, dim3(B), dim3(256), 0, stream,
                       ao, pw, pb, out);
}

// Round 2
// 755.702 us; speedup vs baseline: 4.3826x; 4.3826x over previous
//
#include <hip/hip_runtime.h>
#include <hip/hip_bf16.h>

#define TN 49      // tokens per window
#define TC 192     // channels
#define NH 6       // heads
#define HD 32      // head dim
#define NP 64      // padded tokens
#define XSTR 200   // Xs row stride (bf16 elems) -> 400B, 16B-aligned, 2-way banks
#define QSTR 40    // Qh/Kh row stride -> 80B
#define VSTR 72    // VT row stride -> 144B
#define PSTR 72    // Ps row stride
#define WSTR 200   // Wsh row stride

typedef __bf16 bf16x8 __attribute__((ext_vector_type(8)));
typedef float  f32x4  __attribute__((ext_vector_type(4)));

static constexpr float SCALE = 0.17677669529663687f;  // 32^-0.5

__device__ __forceinline__ unsigned short f2bf(float f) {
    union { float f; unsigned u; } v; v.f = f;
    unsigned r = v.u + 0x7FFFu + ((v.u >> 16) & 1u);   // RNE
    return (unsigned short)(r >> 16);
}

// ---------------------------------------------------------------------------
// Kernel 0: weight fp32 -> bf16 (qkv_w 576x192, proj_w 192x192)
// ---------------------------------------------------------------------------
__global__ __launch_bounds__(256) void wconv_kernel(
    const float* __restrict__ qw, const float* __restrict__ pw,
    unsigned short* __restrict__ qwb, unsigned short* __restrict__ pwb)
{
    int idx = blockIdx.x * 256 + threadIdx.x;
    if (idx < 576 * 192) qwb[idx] = f2bf(qw[idx]);
    else {
        int j = idx - 576 * 192;
        if (j < 192 * 192) pwb[j] = f2bf(pw[j]);
    }
}

// ---------------------------------------------------------------------------
// Kernel 1: fused qkv + attention. One block per window, 4 waves.
// Wave w owns token-row-tile [w*16, w*16+16).
// ---------------------------------------------------------------------------
__global__ __launch_bounds__(256) void attn_kernel(
    const float* __restrict__ x, const float* __restrict__ mask,
    const float* __restrict__ bt, const unsigned short* __restrict__ wqkv,
    const float* __restrict__ qb, const int* __restrict__ ridx,
    unsigned short* __restrict__ ao, int nW)
{
    __shared__ __align__(16) unsigned short Xs[NP * XSTR];   // 25600 B
    __shared__ __align__(16) unsigned short Qh[NP * QSTR];   //  5120 B
    __shared__ __align__(16) unsigned short Kh[NP * QSTR];   //  5120 B
    __shared__ __align__(16) unsigned short VT[HD * VSTR];   //  4608 B
    __shared__ __align__(16) unsigned short PW[32 * WSTR];   // 12800 B (Wsh | Ps overlay)
    // total 53248 B -> 3 blocks/CU

    unsigned short* Wsh = PW;          // qkv phase: 32 x WSTR
    unsigned short* Ps  = PW;          // attn phase: 64 x PSTR (4608 elems <= 6400)

    const int b    = blockIdx.x;
    const int t    = threadIdx.x;
    const int w    = t >> 6;
    const int lane = t & 63;
    const int l15  = lane & 15;
    const int quad = lane >> 4;
    const float NEG_INF = -__builtin_inff();

    // ---- stage x -> bf16 LDS, zero-pad rows 49..63 ----
    {
        const float4* xg = (const float4*)(x + (size_t)b * TN * TC);
        for (int idx = t; idx < NP * (TC / 4); idx += 256) {
            int row = idx / (TC / 4), c4 = idx % (TC / 4);
            unsigned o0 = 0, o1 = 0;
            if (row < TN) {
                float4 v = xg[row * (TC / 4) + c4];
                o0 = (unsigned)f2bf(v.x) | ((unsigned)f2bf(v.y) << 16);
                o1 = (unsigned)f2bf(v.z) | ((unsigned)f2bf(v.w) << 16);
            }
            uint2 u; u.x = o0; u.y = o1;
            *(uint2*)&Xs[row * XSTR + c4 * 4] = u;
        }
    }
    __syncthreads();

    // per-wave A-fragments of x (reused for every head/matrix)
    bf16x8 af[6];
#pragma unroll
    for (int kt = 0; kt < 6; ++kt)
        af[kt] = *(const bf16x8*)&Xs[(w * 16 + l15) * XSTR + kt * 32 + quad * 8];

    const float* maskp = mask + (size_t)(b % nW) * TN * TN;

#pragma unroll 1
    for (int h = 0; h < NH; ++h) {
        // ---- q, k, v for this head via MFMA ----
#pragma unroll 1
        for (int mat = 0; mat < 3; ++mat) {
            __syncthreads();  // protect Wsh/Ps overlay + Qh/Kh/VT reuse across heads
            const uint4* wg = (const uint4*)(wqkv + (size_t)(mat * TC + h * HD) * TC);
            for (int idx = t; idx < 32 * 24; idx += 256) {
                int row = idx / 24, c8 = idx % 24;
                *(uint4*)&Wsh[row * WSTR + c8 * 8] = wg[idx];
            }
            __syncthreads();
#pragma unroll
            for (int ct = 0; ct < 2; ++ct) {
                f32x4 acc = {0.f, 0.f, 0.f, 0.f};
#pragma unroll
                for (int kt = 0; kt < 6; ++kt) {
                    bf16x8 bf = *(const bf16x8*)&Wsh[(ct * 16 + l15) * WSTR + kt * 32 + quad * 8];
                    acc = __builtin_amdgcn_mfma_f32_16x16x32_bf16(af[kt], bf, acc, 0, 0, 0);
                }
                const int d = ct * 16 + l15;
                const float bias = qb[mat * TC + h * HD + d];
#pragma unroll
                for (int r = 0; r < 4; ++r) {
                    int n = w * 16 + quad * 4 + r;
                    float val = acc[r] + bias;
                    if (mat == 0)      Qh[n * QSTR + d] = f2bf(val * SCALE);
                    else if (mat == 1) Kh[n * QSTR + d] = f2bf(val);
                    else               VT[d * VSTR + n] = f2bf(val);
                }
            }
        }
        __syncthreads();  // all waves' Q/K/VT visible

        // ---- S = Q K^T : 4 col-tiles, K=32 ----
        bf16x8 aq = *(const bf16x8*)&Qh[(w * 16 + l15) * QSTR + quad * 8];
        f32x4 sacc[4];
#pragma unroll
        for (int tc = 0; tc < 4; ++tc) {
            bf16x8 bk = *(const bf16x8*)&Kh[(tc * 16 + l15) * QSTR + quad * 8];
            f32x4 z = {0.f, 0.f, 0.f, 0.f};
            sacc[tc] = __builtin_amdgcn_mfma_f32_16x16x32_bf16(aq, bk, z, 0, 0, 0);
        }

        // ---- bias + mask + softmax (rows live in (quad, r); cols in (tc, l15)) ----
        float sv[4][4];
        float mx[4] = {NEG_INF, NEG_INF, NEG_INF, NEG_INF};
#pragma unroll
        for (int tc = 0; tc < 4; ++tc) {
            int m = tc * 16 + l15;
#pragma unroll
            for (int r = 0; r < 4; ++r) {
                int n = w * 16 + quad * 4 + r;
                float s;
                if (m < TN) {
                    s = sacc[tc][r];
                    if (n < TN) {
                        int flat = n * TN + m;
                        s += bt[ridx[flat] * NH + h] + maskp[flat];
                    }
                } else s = NEG_INF;
                sv[tc][r] = s;
                mx[r] = fmaxf(mx[r], s);
            }
        }
#pragma unroll
        for (int r = 0; r < 4; ++r) {
            mx[r] = fmaxf(mx[r], __shfl_xor(mx[r], 1));
            mx[r] = fmaxf(mx[r], __shfl_xor(mx[r], 2));
            mx[r] = fmaxf(mx[r], __shfl_xor(mx[r], 4));
            mx[r] = fmaxf(mx[r], __shfl_xor(mx[r], 8));
        }
        float sm[4] = {0.f, 0.f, 0.f, 0.f};
#pragma unroll
        for (int tc = 0; tc < 4; ++tc)
#pragma unroll
            for (int r = 0; r < 4; ++r) {
                float p = __expf(sv[tc][r] - mx[r]);
                sv[tc][r] = p;
                sm[r] += p;
            }
#pragma unroll
        for (int r = 0; r < 4; ++r) {
            sm[r] += __shfl_xor(sm[r], 1);
            sm[r] += __shfl_xor(sm[r], 2);
            sm[r] += __shfl_xor(sm[r], 4);
            sm[r] += __shfl_xor(sm[r], 8);
            sm[r] = 1.0f / sm[r];
        }
#pragma unroll
        for (int tc = 0; tc < 4; ++tc)
#pragma unroll
            for (int r = 0; r < 4; ++r)
                Ps[(w * 16 + quad * 4 + r) * PSTR + tc * 16 + l15] = f2bf(sv[tc][r] * sm[r]);
        // Ps rows of this tile are produced & consumed by this wave only.

        // ---- out_h = P V : 2 d-tiles, K=64 (2 steps) ----
#pragma unroll
        for (int dt = 0; dt < 2; ++dt) {
            f32x4 pacc = {0.f, 0.f, 0.f, 0.f};
#pragma unroll
            for (int kt = 0; kt < 2; ++kt) {
                bf16x8 ap = *(const bf16x8*)&Ps[(w * 16 + l15) * PSTR + kt * 32 + quad * 8];
                bf16x8 bv = *(const bf16x8*)&VT[(dt * 16 + l15) * VSTR + kt * 32 + quad * 8];
                pacc = __builtin_amdgcn_mfma_f32_16x16x32_bf16(ap, bv, pacc, 0, 0, 0);
            }
#pragma unroll
            for (int r = 0; r < 4; ++r) {
                int n = w * 16 + quad * 4 + r;
                if (n < TN) {
                    int c = h * HD + dt * 16 + l15;
                    ao[((size_t)b * TN + n) * TC + c] = f2bf(pacc[r]);
                }
            }
        }
    }
}

// ---------------------------------------------------------------------------
// Kernel 2: proj GEMM (200704 x 192) @ (192 x 192)^T + bias -> fp32
// ---------------------------------------------------------------------------
__global__ __launch_bounds__(256) void proj_kernel(
    const unsigned short* __restrict__ ao, const unsigned short* __restrict__ wp,
    const float* __restrict__ pb, float* __restrict__ out, int M)
{
    __shared__ __align__(16) unsigned short As[NP * XSTR];   // 25600 B

    const int blk  = blockIdx.x;
    const int t    = threadIdx.x;
    const int w    = t >> 6;
    const int lane = t & 63;
    const int l15  = lane & 15;
    const int quad = lane >> 4;

    {
        const uint4* ag = (const uint4*)(ao + (size_t)blk * 64 * TC);
        for (int idx = t; idx < 64 * 24; idx += 256) {
            int row = idx / 24, c8 = idx % 24;
            uint4 v = {0, 0, 0, 0};
            if (blk * 64 + row < M) v = ag[idx];
            *(uint4*)&As[row * XSTR + c8 * 8] = v;
        }
    }
    __syncthreads();

    bf16x8 af[6];
#pragma unroll
    for (int kt = 0; kt < 6; ++kt)
        af[kt] = *(const bf16x8*)&As[(w * 16 + l15) * XSTR + kt * 32 + quad * 8];

#pragma unroll 1
    for (int ct = 0; ct < 12; ++ct) {
        f32x4 acc = {0.f, 0.f, 0.f, 0.f};
#pragma unroll
        for (int kt = 0; kt < 6; ++kt) {
            bf16x8 bf = *(const bf16x8*)(wp + (size_t)(ct * 16 + l15) * TC + kt * 32 + quad * 8);
            acc = __builtin_amdgcn_mfma_f32_16x16x32_bf16(af[kt], bf, acc, 0, 0, 0);
        }
        const int c = ct * 16 + l15;
        const float bias = pb[c];
#pragma unroll
        for (int r = 0; r < 4; ++r) {
            int gm = blk * 64 + w * 16 + quad * 4 + r;
            if (gm < M) out[(size_t)gm * TC + c] = acc[r] + bias;
        }
    }
}

extern "C" void kernel_launch(void* const* d_in, const int* in_sizes, int n_in,
                              void* d_out, int out_size, void* d_ws, size_t ws_size,
                              hipStream_t stream) {
    const float* x    = (const float*)d_in[0];
    const float* mask = (const float*)d_in[1];
    const float* bt   = (const float*)d_in[2];
    const float* qw   = (const float*)d_in[3];
    const float* qb   = (const float*)d_in[4];
    const float* pw   = (const float*)d_in[5];
    const float* pb   = (const float*)d_in[6];
    const int*   ridx = (const int*)d_in[7];

    const int B  = in_sizes[0] / (TN * TC);   // 4096
    const int nW = in_sizes[1] / (TN * TN);   // 64
    const int M  = B * TN;                    // 200704

    unsigned short* wqkvb = (unsigned short*)d_ws;            // 576*192 bf16
    unsigned short* wpb   = wqkvb + 576 * 192;                // 192*192 bf16
    unsigned short* ao    = wpb + 192 * 192;                  // M*192 bf16 (77 MB)

    hipLaunchKernelGGL(wconv_kernel, dim3(576), dim3(256), 0, stream,
                       qw, pw, wqkvb, wpb);
    hipLaunchKernelGGL(attn_kernel, dim3(B), dim3(256), 0, stream,
                       x, mask, bt, wqkvb, qb, ridx, ao, nW);
    hipLaunchKernelGGL(proj_kernel, dim3((M + 63) / 64), dim3(256), 0, stream,
                       ao, wpb, pb, (float*)d_out, M);
}